// Round 3
// baseline (2732.939 us; speedup 1.0000x reference)
//
#include <hip/hip_runtime.h>
#include <hip/hip_bf16.h>
#include <math.h>

#define LLEN 30
#define DMOD 14
#define NH 8
#define NFF 50
#define NTOP 3
#define MAK 25
#define RP 12
#define LN_EPS 1e-5f

typedef unsigned short u16;
typedef unsigned int u32;

__device__ __forceinline__ float bflo(u32 v) {
  union { u32 u; float f; } w; w.u = v << 16; return w.f;
}
__device__ __forceinline__ float bfhi(u32 v) {
  union { u32 u; float f; } w; w.u = v & 0xFFFF0000u; return w.f;
}
__device__ __forceinline__ u16 f2bf(float f) {
  union { float f; u32 u; } w; w.f = f;
  u32 x = w.u;
  x = (x + 0x7FFFu + ((x >> 16) & 1u)) >> 16;
  return (u16)x;
}
__device__ __forceinline__ void unpack8(uint4 v, float* w) {
  w[0] = bflo(v.x); w[1] = bfhi(v.x);
  w[2] = bflo(v.y); w[3] = bfhi(v.y);
  w[4] = bflo(v.z); w[5] = bfhi(v.z);
  w[6] = bflo(v.w); w[7] = bfhi(v.w);
}

// ============================ Front-end kernel ==============================
// One wave per sample; all inputs fp32. ~18 KB LDS.
__global__ __launch_bounds__(64) void fe_kernel(
    const float* __restrict__ x,
    const float* __restrict__ W_emb, const float* __restrict__ b_emb,
    const float* __restrict__ Wq, const float* __restrict__ bq,
    const float* __restrict__ Wk, const float* __restrict__ bk,
    const float* __restrict__ Wv, const float* __restrict__ bv,
    const float* __restrict__ Wo, const float* __restrict__ bo,
    const float* __restrict__ W_ff1, const float* __restrict__ W_ff2,
    const float* __restrict__ g_norm, const float* __restrict__ b_norm,
    const float* __restrict__ W_dy, const float* __restrict__ b_dy,
    const float* __restrict__ channels,
    u16* __restrict__ f_out)
{
  const int b = blockIdx.x;
  const int t = threadIdx.x;

  __shared__ float bx[LLEN * 16];   // raw x, later x2 / s2
  __shared__ float be[LLEN * 16];   // conv embed, later LN out
  __shared__ float ba[LLEN * 16];   // x1 / s1, later DyConv h1 (flat 420)
  __shared__ float bm[LLEN * 16];   // moving-average mean
  __shared__ float qb[NH * LLEN], kb[NH * LLEN], vb[NH * LLEN];
  __shared__ float bg[LLEN * 52];   // gelu activations
  __shared__ float mv[LLEN];
  __shared__ float adjS[DMOD * DMOD];
  __shared__ float tw[NTOP];
  __shared__ int   td[NTOP];

  // ---- load x (row stride 16), adjacency softmax ----
  const float* xb = x + (size_t)b * (LLEN * DMOD);
  for (int i = t; i < LLEN * DMOD; i += 64) {
    int l = i / DMOD, d = i - l * DMOD;
    bx[l * 16 + d] = xb[i];
  }
  if (t < DMOD) {
    float m = -1e30f;
    for (int j = 0; j < DMOD; ++j) m = fmaxf(m, channels[t * DMOD + j]);
    float s = 0.f;
    for (int j = 0; j < DMOD; ++j) s += __expf(channels[t * DMOD + j] - m);
    float inv = 1.f / s;
    for (int j = 0; j < DMOD; ++j)
      adjS[t * DMOD + j] = __expf(channels[t * DMOD + j] - m) * inv;
  }
  __syncthreads();

  // ---- conv1d embed (k=3, zero pad 1) ----
  for (int i = t; i < LLEN * DMOD; i += 64) {
    int l = i / DMOD, o = i - l * DMOD;
    float acc = b_emb[o];
    for (int dt = 0; dt < 3; ++dt) {
      int ll = l + dt - 1;
      if (ll >= 0 && ll < LLEN) {
        for (int c = 0; c < DMOD; ++c)
          acc += W_emb[o * (DMOD * 3) + c * 3 + dt] * bx[ll * 16 + c];
      }
    }
    be[l * 16 + o] = acc;
  }
  __syncthreads();

  // ---- q, k, v projections ----
  for (int i = t; i < NH * LLEN; i += 64) {
    int h = i / LLEN, l = i - h * LLEN;
    float acc = bq[h];
    for (int d = 0; d < DMOD; ++d) acc += Wq[d * NH + h] * be[l * 16 + d];
    qb[i] = acc;
  }
  for (int i = t; i < NH * LLEN; i += 64) {
    int h = i / LLEN, l = i - h * LLEN;
    float acc = bk[h];
    for (int d = 0; d < DMOD; ++d) acc += Wk[d * NH + h] * be[l * 16 + d];
    kb[i] = acc;
  }
  for (int i = t; i < NH * LLEN; i += 64) {
    int h = i / LLEN, l = i - h * LLEN;
    float acc = bv[h];
    for (int d = 0; d < DMOD; ++d) acc += Wv[d * NH + h] * be[l * 16 + d];
    vb[i] = acc;
  }
  __syncthreads();

  // ---- circular autocorrelation mean over heads: one thread per tau ----
  if (t < LLEN) {
    const int tau = t;
    float acc = 0.f;
    for (int h = 0; h < NH; ++h) {
      float a = 0.f;
      for (int s = 0; s < LLEN; ++s) {
        int sp = s + tau; if (sp >= LLEN) sp -= LLEN;
        a += qb[h * LLEN + sp] * kb[h * LLEN + s];
      }
      acc += a;
    }
    mv[tau] = acc * (1.f / NH);
  }
  __syncthreads();

  // ---- top-3 + softmax (strict > keeps lowest index on ties = lax.top_k) ----
  if (t == 0) {
    float v1 = -1e30f, v2 = -1e30f, v3 = -1e30f; int i1 = 0, i2 = 0, i3 = 0;
    for (int i = 0; i < LLEN; ++i) {
      float v = mv[i];
      if (v > v1)      { v3 = v2; i3 = i2; v2 = v1; i2 = i1; v1 = v; i1 = i; }
      else if (v > v2) { v3 = v2; i3 = i2; v2 = v; i2 = i; }
      else if (v > v3) { v3 = v; i3 = i; }
    }
    float e1 = 1.f, e2 = __expf(v2 - v1), e3 = __expf(v3 - v1);
    float inv = 1.f / (e1 + e2 + e3);
    tw[0] = e1 * inv; tw[1] = e2 * inv; tw[2] = e3 * inv;
    td[0] = i1; td[1] = i2; td[2] = i3;
  }
  __syncthreads();

  // ---- weighted circular gather + out-proj + residual ----
  for (int i = t; i < LLEN * DMOD; i += 64) {
    int l = i / DMOD, d = i - l * DMOD;
    float acc = bo[d];
    for (int h = 0; h < NH; ++h) {
      float agg = 0.f;
      for (int k2 = 0; k2 < NTOP; ++k2) {
        int idx2 = l + td[k2]; if (idx2 >= LLEN) idx2 -= LLEN;
        agg += tw[k2] * vb[h * LLEN + idx2];
      }
      acc += agg * Wo[h * DMOD + d];
    }
    ba[l * 16 + d] = be[l * 16 + d] + acc;
  }
  __syncthreads();

  // ---- series_decomp #1 ----
  for (int i = t; i < LLEN * DMOD; i += 64) {
    int l = i / DMOD, d = i - l * DMOD;
    float s = 0.f;
    for (int j = 0; j < MAK; ++j) {
      int ll = l + j - RP; ll = ll < 0 ? 0 : (ll > LLEN - 1 ? LLEN - 1 : ll);
      s += ba[ll * 16 + d];
    }
    bm[l * 16 + d] = s * (1.f / MAK);
  }
  __syncthreads();
  for (int i = t; i < LLEN * DMOD; i += 64) {
    int l = i / DMOD, d = i - l * DMOD;
    ba[l * 16 + d] -= bm[l * 16 + d];         // ba = s1
  }
  __syncthreads();

  // ---- FFN stage A: gelu(s1 @ W_ff1) ----
  for (int i = t; i < LLEN * NFF; i += 64) {
    int l = i / NFF, f = i - l * NFF;
    float a = 0.f;
    for (int d = 0; d < DMOD; ++d) a += ba[l * 16 + d] * W_ff1[d * NFF + f];
    bg[l * 52 + f] = 0.5f * a * (1.f + erff(a * 0.70710678118654752f));
  }
  __syncthreads();

  // ---- FFN stage B: x2 = s1 + bg @ W_ff2 ----
  for (int i = t; i < LLEN * DMOD; i += 64) {
    int l = i / DMOD, d = i - l * DMOD;
    float y = 0.f;
    for (int f = 0; f < NFF; ++f) y += bg[l * 52 + f] * W_ff2[f * DMOD + d];
    bx[l * 16 + d] = ba[l * 16 + d] + y;
  }
  __syncthreads();

  // ---- series_decomp #2 ----
  for (int i = t; i < LLEN * DMOD; i += 64) {
    int l = i / DMOD, d = i - l * DMOD;
    float s = 0.f;
    for (int j = 0; j < MAK; ++j) {
      int ll = l + j - RP; ll = ll < 0 ? 0 : (ll > LLEN - 1 ? LLEN - 1 : ll);
      s += bx[ll * 16 + d];
    }
    bm[l * 16 + d] = s * (1.f / MAK);
  }
  __syncthreads();
  for (int i = t; i < LLEN * DMOD; i += 64) {
    int l = i / DMOD, d = i - l * DMOD;
    bx[l * 16 + d] -= bm[l * 16 + d];         // bx = s2
  }
  __syncthreads();

  // ---- LayerNorm over D ----
  if (t < LLEN) {
    const int l = t;
    float m = 0.f;
    for (int d = 0; d < DMOD; ++d) m += bx[l * 16 + d];
    m *= (1.f / DMOD);
    float v2 = 0.f;
    for (int d = 0; d < DMOD; ++d) { float z = bx[l * 16 + d] - m; v2 += z * z; }
    v2 *= (1.f / DMOD);
    float inv = rsqrtf(v2 + LN_EPS);
    for (int d = 0; d < DMOD; ++d)
      be[l * 16 + d] = (bx[l * 16 + d] - m) * inv * g_norm[d] + b_norm[d];
  }
  __syncthreads();

  // ---- DyConv time-linear: h1[d*30+l] (flat in ba) ----
  for (int i = t; i < DMOD * LLEN; i += 64) {
    int d = i / LLEN, l = i - d * LLEN;
    float acc = b_dy[l];
    for (int lp = 0; lp < LLEN; ++lp) acc += be[lp * 16 + d] * W_dy[lp * LLEN + l];
    ba[i] = acc;
  }
  __syncthreads();

  // ---- dy = relu(adj @ h1); write f (bf16) ----
  for (int i = t; i < DMOD * LLEN; i += 64) {
    int d2 = i / LLEN, l = i - d2 * LLEN;
    float acc = 0.f;
    for (int j = 0; j < DMOD; ++j) acc += adjS[d2 * DMOD + j] * ba[j * LLEN + l];
    f_out[(size_t)b * (DMOD * LLEN) + i] = f2bf(fmaxf(acc, 0.f));
  }
}

// ============================ MLP head kernel ===============================
#define SB 32
#define TI 32

__global__ __launch_bounds__(256, 2) void head_kernel(
    const u16* __restrict__ fin,
    const float* __restrict__ W1, const float* __restrict__ b1,
    const float* __restrict__ W2, const float* __restrict__ b2,
    const float* __restrict__ Wres, const float* __restrict__ bres,
    const float* __restrict__ g_ln, const float* __restrict__ b_ln,
    const float* __restrict__ W3, const float* __restrict__ b3,
    float* __restrict__ out, int Btot)
{
  const int t = threadIdx.x;
  const int b0 = blockIdx.x * SB;

  __shared__ __align__(16) u32 fT32[420 * 18];  // f, 2 bf16 samples / u32
  __shared__ __align__(16) u32 w1t[TI * 128];   // W1 tile, 2 bf16 cols / u32
  __shared__ __align__(16) u32 h32[SB * 132];   // h rows, 2 bf16 / u32

  // fill fT32: pack samples (2sp, 2sp+1)
  for (int idx = t; idx < (SB / 2) * 420; idx += 256) {
    int sp = idx / 420, i = idx - sp * 420;
    int g0 = b0 + 2 * sp, g1 = g0 + 1;
    u32 lo = (g0 < Btot) ? (u32)fin[(size_t)g0 * 420 + i] : 0u;
    u32 hi = (g1 < Btot) ? (u32)fin[(size_t)g1 * 420 + i] : 0u;
    fT32[i * 18 + sp] = lo | (hi << 16);
  }

  const int jg = t >> 3;          // 0..31 : 8 output cols each
  const int sg = t & 7;           // 0..7  : 4 samples each
  const int j0 = jg * 8;

  float acc[4][8];
  #pragma unroll
  for (int u = 0; u < 4; ++u)
    #pragma unroll
    for (int e = 0; e < 8; ++e) acc[u][e] = 0.f;

  for (int i0 = 0; i0 < 420; i0 += TI) {
    const int ti = (420 - i0) < TI ? (420 - i0) : TI;
    __syncthreads();
    for (int idx = t; idx < ti * 128; idx += 256) {
      int r = idx >> 7, cp = idx & 127;
      float2 wf = *((const float2*)&W1[(size_t)(i0 + r) * 256 + 2 * cp]);
      w1t[idx] = (u32)f2bf(wf.x) | ((u32)f2bf(wf.y) << 16);
    }
    __syncthreads();
    for (int ii = 0; ii < ti; ++ii) {
      uint2 fv = *((const uint2*)&fT32[(i0 + ii) * 18 + sg * 2]);
      float f0 = bflo(fv.x), f1 = bfhi(fv.x), f2v = bflo(fv.y), f3 = bfhi(fv.y);
      uint4 wv = *((const uint4*)&w1t[ii * 128 + jg * 4]);
      float w[8];
      unpack8(wv, w);
      #pragma unroll
      for (int e = 0; e < 8; ++e) {
        acc[0][e] += f0 * w[e];
        acc[1][e] += f1 * w[e];
        acc[2][e] += f2v * w[e];
        acc[3][e] += f3 * w[e];
      }
    }
  }
  __syncthreads();

  // bias + relu, pack h rows (bf16 pairs)
  #pragma unroll
  for (int u = 0; u < 4; ++u) {
    uint4 pk;
    u32 p[4];
    #pragma unroll
    for (int q = 0; q < 4; ++q) {
      float a = fmaxf(acc[u][2 * q]     + b1[j0 + 2 * q], 0.f);
      float c = fmaxf(acc[u][2 * q + 1] + b1[j0 + 2 * q + 1], 0.f);
      p[q] = (u32)f2bf(a) | ((u32)f2bf(c) << 16);
    }
    pk.x = p[0]; pk.y = p[1]; pk.z = p[2]; pk.w = p[3];
    *((uint4*)&h32[(sg * 4 + u) * 132 + jg * 4]) = pk;
  }
  __syncthreads();

  // stage 2: thread = (sample s2, cols c8..c8+7)
  const int s2 = t >> 3;
  const int c8 = (t & 7) * 8;
  float a2[8];
  #pragma unroll
  for (int e = 0; e < 8; ++e) a2[e] = b2[c8 + e] + bres[c8 + e];

  for (int i2 = 0; i2 < 128; ++i2) {
    u32 hp = h32[s2 * 132 + i2];
    float h0 = bflo(hp), h1v = bfhi(hp);
    float4 wa0 = *((const float4*)&W2[(size_t)(2 * i2) * 64 + c8]);
    float4 wa1 = *((const float4*)&W2[(size_t)(2 * i2) * 64 + c8 + 4]);
    float4 wb0 = *((const float4*)&W2[(size_t)(2 * i2 + 1) * 64 + c8]);
    float4 wb1 = *((const float4*)&W2[(size_t)(2 * i2 + 1) * 64 + c8 + 4]);
    a2[0] += h0 * wa0.x + h1v * wb0.x;
    a2[1] += h0 * wa0.y + h1v * wb0.y;
    a2[2] += h0 * wa0.z + h1v * wb0.z;
    a2[3] += h0 * wa0.w + h1v * wb0.w;
    a2[4] += h0 * wa1.x + h1v * wb1.x;
    a2[5] += h0 * wa1.y + h1v * wb1.y;
    a2[6] += h0 * wa1.z + h1v * wb1.z;
    a2[7] += h0 * wa1.w + h1v * wb1.w;
  }
  const int spair = s2 >> 1;
  const int shalf = s2 & 1;
  for (int i = 0; i < 420; ++i) {
    u32 fp2 = fT32[i * 18 + spair];
    float fv = shalf ? bfhi(fp2) : bflo(fp2);
    float4 wr0 = *((const float4*)&Wres[(size_t)i * 64 + c8]);
    float4 wr1 = *((const float4*)&Wres[(size_t)i * 64 + c8 + 4]);
    a2[0] += fv * wr0.x; a2[1] += fv * wr0.y;
    a2[2] += fv * wr0.z; a2[3] += fv * wr0.w;
    a2[4] += fv * wr1.x; a2[5] += fv * wr1.y;
    a2[6] += fv * wr1.z; a2[7] += fv * wr1.w;
  }

  // LN over 64 (8 lanes x 8 regs) then @W3 + b3
  float s1 = 0.f, sq = 0.f;
  #pragma unroll
  for (int e = 0; e < 8; ++e) { s1 += a2[e]; sq += a2[e] * a2[e]; }
  s1 += __shfl_xor(s1, 1); s1 += __shfl_xor(s1, 2); s1 += __shfl_xor(s1, 4);
  sq += __shfl_xor(sq, 1); sq += __shfl_xor(sq, 2); sq += __shfl_xor(sq, 4);
  float mean = s1 * (1.f / 64.f);
  float var = sq * (1.f / 64.f) - mean * mean;
  float inv = rsqrtf(var + LN_EPS);
  float pr = 0.f;
  #pragma unroll
  for (int e = 0; e < 8; ++e) {
    float n = (a2[e] - mean) * inv * g_ln[c8 + e] + b_ln[c8 + e];
    pr += n * W3[c8 + e];
  }
  pr += __shfl_xor(pr, 1); pr += __shfl_xor(pr, 2); pr += __shfl_xor(pr, 4);
  if ((t & 7) == 0 && (b0 + s2) < Btot) out[b0 + s2] = pr + b3[0];
}

extern "C" void kernel_launch(void* const* d_in, const int* in_sizes, int n_in,
                              void* d_out, int out_size, void* d_ws, size_t ws_size,
                              hipStream_t stream) {
  const float* x        = (const float*)d_in[0];
  const float* W_emb    = (const float*)d_in[1];
  const float* b_emb    = (const float*)d_in[2];
  const float* Wq       = (const float*)d_in[3];
  const float* bq       = (const float*)d_in[4];
  const float* Wk       = (const float*)d_in[5];
  const float* bk       = (const float*)d_in[6];
  const float* Wv       = (const float*)d_in[7];
  const float* bv       = (const float*)d_in[8];
  const float* Wo       = (const float*)d_in[9];
  const float* bo       = (const float*)d_in[10];
  const float* W_ff1    = (const float*)d_in[11];
  const float* W_ff2    = (const float*)d_in[12];
  const float* g_norm   = (const float*)d_in[13];
  const float* b_norm   = (const float*)d_in[14];
  const float* W_dy     = (const float*)d_in[15];
  const float* b_dy     = (const float*)d_in[16];
  const float* channels = (const float*)d_in[17];
  const float* W1       = (const float*)d_in[18];
  const float* b1       = (const float*)d_in[19];
  const float* W2       = (const float*)d_in[20];
  const float* b2       = (const float*)d_in[21];
  const float* Wres     = (const float*)d_in[22];
  const float* bres     = (const float*)d_in[23];
  const float* g_ln     = (const float*)d_in[24];
  const float* b_ln     = (const float*)d_in[25];
  const float* W3       = (const float*)d_in[26];
  const float* b3       = (const float*)d_in[27];

  const int B = in_sizes[0] / (LLEN * DMOD);
  u16* fbuf = (u16*)d_ws;   // B*420 bf16 ≈ 55 MB scratch

  fe_kernel<<<B, 64, 0, stream>>>(x, W_emb, b_emb, Wq, bq, Wk, bk, Wv, bv, Wo, bo,
                                  W_ff1, W_ff2, g_norm, b_norm, W_dy, b_dy, channels,
                                  fbuf);

  const int nb = (B + SB - 1) / SB;
  head_kernel<<<nb, 256, 0, stream>>>(fbuf, W1, b1, W2, b2, Wres, bres,
                                      g_ln, b_ln, W3, b3, (float*)d_out, B);
}

// Round 5
// 2083.425 us; speedup vs baseline: 1.3118x; 1.3118x over previous
//
#include <hip/hip_runtime.h>
#include <hip/hip_bf16.h>
#include <math.h>

#define LLEN 30
#define DMOD 14
#define NH 8
#define NFF 50
#define NTOP 3
#define MAK 25
#define RP 12
#define LN_EPS 1e-5f

typedef unsigned short u16;
typedef unsigned int u32;

__device__ __forceinline__ float bflo(u32 v) {
  union { u32 u; float f; } w; w.u = v << 16; return w.f;
}
__device__ __forceinline__ float bfhi(u32 v) {
  union { u32 u; float f; } w; w.u = v & 0xFFFF0000u; return w.f;
}
__device__ __forceinline__ u16 f2bf(float f) {
  union { float f; u32 u; } w; w.f = f;
  u32 x = w.u;
  x = (x + 0x7FFFu + ((x >> 16) & 1u)) >> 16;
  return (u16)x;
}
__device__ __forceinline__ void unpack8(uint4 v, float* w) {
  w[0] = bflo(v.x); w[1] = bfhi(v.x);
  w[2] = bflo(v.y); w[3] = bfhi(v.y);
  w[4] = bflo(v.z); w[5] = bfhi(v.z);
  w[6] = bflo(v.w); w[7] = bfhi(v.w);
}

// Exact replicate-pad 25-tap moving-average removal, one row (30 vals) in regs.
// row is one channel's time series at stride 1. In-place: row <- row - MA(row).
__device__ __forceinline__ void decomp_row(float* row) {
  float xv[30];
  #pragma unroll
  for (int j = 0; j < 30; ++j) xv[j] = row[j];
  float ws = 13.f * xv[0];
  #pragma unroll
  for (int j = 1; j <= 12; ++j) ws += xv[j];
  row[0] = xv[0] - ws * (1.f / 25.f);
  #pragma unroll
  for (int l = 1; l < 30; ++l) {
    const int hi = (l + 12 > 29) ? 29 : l + 12;
    const int lo = (l - 13 < 0) ? 0 : l - 13;
    ws += xv[hi] - xv[lo];
    row[l] = xv[l] - ws * (1.f / 25.f);
  }
}

// ============================ Front-end kernel ==============================
// One wave per sample. Activations in LDS as [d][l] stride 32 (bank = l).
// ~9.3 KB LDS -> 16 blocks/CU with __launch_bounds__(64,4).
__global__ __launch_bounds__(64, 4) void fe_kernel(
    const float* __restrict__ x,
    const float* __restrict__ W_emb, const float* __restrict__ b_emb,
    const float* __restrict__ Wq, const float* __restrict__ bq,
    const float* __restrict__ Wk, const float* __restrict__ bk,
    const float* __restrict__ Wv, const float* __restrict__ bv,
    const float* __restrict__ Wo, const float* __restrict__ bo,
    const float* __restrict__ W_ff1, const float* __restrict__ W_ff2,
    const float* __restrict__ g_norm, const float* __restrict__ b_norm,
    const float* __restrict__ W_dy, const float* __restrict__ b_dy,
    const float* __restrict__ channels,
    u16* __restrict__ f_out)
{
  const int b = blockIdx.x;
  const int t = threadIdx.x;

  __shared__ float bx[DMOD * 32];  // raw x -> x2 -> s2
  __shared__ float be[DMOD * 32];  // embed -> LN out
  __shared__ float ba[DMOD * 32];  // x1 -> s1 -> DyConv h1
  __shared__ float qb[NH * 32];    // q -> agg
  __shared__ float kb[NH * 32];    // k
  __shared__ float vb[NH * 32];    // v
  __shared__ float mv[32];
  __shared__ float adjS[DMOD * DMOD];
  __shared__ float tw[NTOP];
  __shared__ int   td[NTOP];

  // ---- load x transposed: bx[d*32+l] = x[b][l][d]; adjacency softmax ----
  const float* xb = x + (size_t)b * (LLEN * DMOD);
  for (int i = t; i < DMOD * 32; i += 64) {
    const int d = i >> 5, l = i & 31;
    if (l < LLEN) bx[i] = xb[l * DMOD + d];
  }
  if (t < DMOD) {
    float row[DMOD];
    float m = -1e30f;
    #pragma unroll
    for (int j = 0; j < DMOD; ++j) { row[j] = channels[t * DMOD + j]; m = fmaxf(m, row[j]); }
    float s = 0.f;
    #pragma unroll
    for (int j = 0; j < DMOD; ++j) { row[j] = __expf(row[j] - m); s += row[j]; }
    const float inv = 1.f / s;
    #pragma unroll
    for (int j = 0; j < DMOD; ++j) adjS[t * DMOD + j] = row[j] * inv;
  }
  __syncthreads();

  // ---- conv1d embed (k=3, zero pad 1): be[o][l] ----
  for (int i = t; i < DMOD * 32; i += 64) {
    const int o = i >> 5, l = i & 31;
    if (l < LLEN) {
      float acc = b_emb[o];
      #pragma unroll
      for (int dt = 0; dt < 3; ++dt) {
        const int ll = l + dt - 1;
        if ((unsigned)ll < (unsigned)LLEN) {
          #pragma unroll
          for (int c = 0; c < DMOD; ++c)
            acc += W_emb[o * (DMOD * 3) + c * 3 + dt] * bx[c * 32 + ll];
        }
      }
      be[i] = acc;
    }
  }
  __syncthreads();

  // ---- q,k,v projections: [h][l] stride 32 ----
  for (int i = t; i < NH * 32; i += 64) {
    const int h = i >> 5, l = i & 31;
    if (l < LLEN) {
      float acc = bq[h];
      #pragma unroll
      for (int d = 0; d < DMOD; ++d) acc += Wq[d * NH + h] * be[d * 32 + l];
      qb[i] = acc;
    }
  }
  for (int i = t; i < NH * 32; i += 64) {
    const int h = i >> 5, l = i & 31;
    if (l < LLEN) {
      float acc = bk[h];
      #pragma unroll
      for (int d = 0; d < DMOD; ++d) acc += Wk[d * NH + h] * be[d * 32 + l];
      kb[i] = acc;
    }
  }
  for (int i = t; i < NH * 32; i += 64) {
    const int h = i >> 5, l = i & 31;
    if (l < LLEN) {
      float acc = bv[h];
      #pragma unroll
      for (int d = 0; d < DMOD; ++d) acc += Wv[d * NH + h] * be[d * 32 + l];
      vb[i] = acc;
    }
  }
  __syncthreads();

  // ---- circular autocorrelation mean: lane = (tau, head-half) ----
  {
    float part = 0.f;
    const int tau = t >> 1;
    const int h0 = (t & 1) * 4;
    if (tau < LLEN) {
      for (int h = h0; h < h0 + 4; ++h) {
        float a = 0.f;
        #pragma unroll 6
        for (int s = 0; s < LLEN; ++s) {
          int sp = s + tau; if (sp >= LLEN) sp -= LLEN;
          a += qb[h * 32 + sp] * kb[h * 32 + s];
        }
        part += a;
      }
    }
    part += __shfl_xor(part, 1);
    if (tau < LLEN && (t & 1) == 0) mv[tau] = part * (1.f / NH);
  }
  __syncthreads();

  // ---- top-3 + softmax (strict > keeps lowest index on ties = lax.top_k) ----
  if (t == 0) {
    float v1 = -1e30f, v2 = -1e30f, v3 = -1e30f; int i1 = 0, i2 = 0, i3 = 0;
    for (int i = 0; i < LLEN; ++i) {
      const float v = mv[i];
      if (v > v1)      { v3 = v2; i3 = i2; v2 = v1; i2 = i1; v1 = v; i1 = i; }
      else if (v > v2) { v3 = v2; i3 = i2; v2 = v; i2 = i; }
      else if (v > v3) { v3 = v; i3 = i; }
    }
    const float e1 = 1.f, e2 = __expf(v2 - v1), e3 = __expf(v3 - v1);
    const float inv = 1.f / (e1 + e2 + e3);
    tw[0] = e1 * inv; tw[1] = e2 * inv; tw[2] = e3 * inv;
    td[0] = i1; td[1] = i2; td[2] = i3;
  }
  __syncthreads();

  // ---- weighted circular gather: agg -> qb (q dead) ----
  {
    const float w0 = tw[0], w1 = tw[1], w2 = tw[2];
    const int d0 = td[0], d1 = td[1], d2 = td[2];
    for (int i = t; i < NH * 32; i += 64) {
      const int h = i >> 5, l = i & 31;
      if (l < LLEN) {
        int ia = l + d0; if (ia >= LLEN) ia -= LLEN;
        int ib = l + d1; if (ib >= LLEN) ib -= LLEN;
        int ic = l + d2; if (ic >= LLEN) ic -= LLEN;
        qb[i] = w0 * vb[h * 32 + ia] + w1 * vb[h * 32 + ib] + w2 * vb[h * 32 + ic];
      }
    }
  }
  __syncthreads();

  // ---- out-proj + residual: ba[d][l] = be[d][l] + agg@Wo + bo ----
  for (int i = t; i < DMOD * 32; i += 64) {
    const int d = i >> 5, l = i & 31;
    if (l < LLEN) {
      float acc = bo[d];
      #pragma unroll
      for (int h = 0; h < NH; ++h) acc += qb[h * 32 + l] * Wo[h * DMOD + d];
      ba[i] = be[i] + acc;
    }
  }
  __syncthreads();

  // ---- series_decomp #1 (in-register per d-row): ba = s1 ----
  if (t < DMOD) decomp_row(&ba[t * 32]);
  __syncthreads();

  // ---- FFN fused: lane = (l, f-half); x2 = s1 + gelu(s1@W_ff1)@W_ff2 -> bx ----
  {
    const int l = t >> 1;
    const int half = t & 1;
    if (l < LLEN) {
      float sr[DMOD];
      #pragma unroll
      for (int d = 0; d < DMOD; ++d) sr[d] = ba[d * 32 + l];
      float y[DMOD];
      #pragma unroll
      for (int d = 0; d < DMOD; ++d) y[d] = 0.f;
      const int f0 = half * 25;
      for (int f = f0; f < f0 + 25; ++f) {
        float a = 0.f;
        #pragma unroll
        for (int d = 0; d < DMOD; ++d) a += sr[d] * W_ff1[d * NFF + f];
        const float g = 0.5f * a * (1.f + erff(a * 0.70710678118654752f));
        #pragma unroll
        for (int d = 0; d < DMOD; ++d) y[d] += g * W_ff2[f * DMOD + d];
      }
      #pragma unroll
      for (int d = 0; d < DMOD; ++d) y[d] += __shfl_xor(y[d], 1);
      if (half == 0) {
        #pragma unroll
        for (int d = 0; d < DMOD; ++d) bx[d * 32 + l] = sr[d] + y[d];
      }
    }
  }
  __syncthreads();

  // ---- series_decomp #2: bx = s2 ----
  if (t < DMOD) decomp_row(&bx[t * 32]);
  __syncthreads();

  // ---- LayerNorm over D (lane per l) -> be ----
  if (t < LLEN) {
    const int l = t;
    float m = 0.f;
    #pragma unroll
    for (int d = 0; d < DMOD; ++d) m += bx[d * 32 + l];
    m *= (1.f / DMOD);
    float v2 = 0.f;
    #pragma unroll
    for (int d = 0; d < DMOD; ++d) { const float z = bx[d * 32 + l] - m; v2 += z * z; }
    v2 *= (1.f / DMOD);
    const float inv = rsqrtf(v2 + LN_EPS);
    #pragma unroll
    for (int d = 0; d < DMOD; ++d)
      be[d * 32 + l] = (bx[d * 32 + l] - m) * inv * g_norm[d] + b_norm[d];
  }
  __syncthreads();

  // ---- DyConv time-linear: h1[d][l] -> ba ----
  for (int i = t; i < DMOD * 32; i += 64) {
    const int d = i >> 5, l = i & 31;
    if (l < LLEN) {
      float acc = b_dy[l];
      #pragma unroll 6
      for (int lp = 0; lp < LLEN; ++lp) acc += be[d * 32 + lp] * W_dy[lp * LLEN + l];
      ba[i] = acc;
    }
  }
  __syncthreads();

  // ---- dy = relu(adj @ h1); write f (bf16), f index = d2*30+l ----
  for (int i = t; i < DMOD * 32; i += 64) {
    const int d2 = i >> 5, l = i & 31;
    if (l < LLEN) {
      float acc = 0.f;
      #pragma unroll
      for (int j = 0; j < DMOD; ++j) acc += adjS[d2 * DMOD + j] * ba[j * 32 + l];
      f_out[(size_t)b * (DMOD * LLEN) + d2 * LLEN + l] = f2bf(fmaxf(acc, 0.f));
    }
  }
}

// ============================ MLP head kernel ===============================
#define SB 32
#define TI 32

__global__ __launch_bounds__(256, 2) void head_kernel(
    const u16* __restrict__ fin,
    const float* __restrict__ W1, const float* __restrict__ b1,
    const float* __restrict__ W2, const float* __restrict__ b2,
    const float* __restrict__ Wres, const float* __restrict__ bres,
    const float* __restrict__ g_ln, const float* __restrict__ b_ln,
    const float* __restrict__ W3, const float* __restrict__ b3,
    float* __restrict__ out, int Btot)
{
  const int t = threadIdx.x;
  const int b0 = blockIdx.x * SB;

  __shared__ __align__(16) u32 fT32[420 * 18];  // f, 2 bf16 samples / u32
  __shared__ __align__(16) u32 w1t[TI * 128];   // W1 tile, 2 bf16 cols / u32
  __shared__ __align__(16) u32 h32[SB * 132];   // h rows, 2 bf16 / u32

  for (int idx = t; idx < (SB / 2) * 420; idx += 256) {
    int sp = idx / 420, i = idx - sp * 420;
    int g0 = b0 + 2 * sp, g1 = g0 + 1;
    u32 lo = (g0 < Btot) ? (u32)fin[(size_t)g0 * 420 + i] : 0u;
    u32 hi = (g1 < Btot) ? (u32)fin[(size_t)g1 * 420 + i] : 0u;
    fT32[i * 18 + sp] = lo | (hi << 16);
  }

  const int jg = t >> 3;
  const int sg = t & 7;
  const int j0 = jg * 8;

  float acc[4][8];
  #pragma unroll
  for (int u = 0; u < 4; ++u)
    #pragma unroll
    for (int e = 0; e < 8; ++e) acc[u][e] = 0.f;

  for (int i0 = 0; i0 < 420; i0 += TI) {
    const int ti = (420 - i0) < TI ? (420 - i0) : TI;
    __syncthreads();
    for (int idx = t; idx < ti * 128; idx += 256) {
      int r = idx >> 7, cp = idx & 127;
      float2 wf = *((const float2*)&W1[(size_t)(i0 + r) * 256 + 2 * cp]);
      w1t[idx] = (u32)f2bf(wf.x) | ((u32)f2bf(wf.y) << 16);
    }
    __syncthreads();
    for (int ii = 0; ii < ti; ++ii) {
      uint2 fv = *((const uint2*)&fT32[(i0 + ii) * 18 + sg * 2]);
      float f0 = bflo(fv.x), f1 = bfhi(fv.x), f2v = bflo(fv.y), f3 = bfhi(fv.y);
      uint4 wv = *((const uint4*)&w1t[ii * 128 + jg * 4]);
      float w[8];
      unpack8(wv, w);
      #pragma unroll
      for (int e = 0; e < 8; ++e) {
        acc[0][e] += f0 * w[e];
        acc[1][e] += f1 * w[e];
        acc[2][e] += f2v * w[e];
        acc[3][e] += f3 * w[e];
      }
    }
  }
  __syncthreads();

  #pragma unroll
  for (int u = 0; u < 4; ++u) {
    uint4 pk;
    u32 p[4];
    #pragma unroll
    for (int q = 0; q < 4; ++q) {
      float a = fmaxf(acc[u][2 * q]     + b1[j0 + 2 * q], 0.f);
      float c = fmaxf(acc[u][2 * q + 1] + b1[j0 + 2 * q + 1], 0.f);
      p[q] = (u32)f2bf(a) | ((u32)f2bf(c) << 16);
    }
    pk.x = p[0]; pk.y = p[1]; pk.z = p[2]; pk.w = p[3];
    *((uint4*)&h32[(sg * 4 + u) * 132 + jg * 4]) = pk;
  }
  __syncthreads();

  const int s2 = t >> 3;
  const int c8 = (t & 7) * 8;
  float a2[8];
  #pragma unroll
  for (int e = 0; e < 8; ++e) a2[e] = b2[c8 + e] + bres[c8 + e];

  for (int i2 = 0; i2 < 128; ++i2) {
    u32 hp = h32[s2 * 132 + i2];
    float h0 = bflo(hp), h1v = bfhi(hp);
    float4 wa0 = *((const float4*)&W2[(size_t)(2 * i2) * 64 + c8]);
    float4 wa1 = *((const float4*)&W2[(size_t)(2 * i2) * 64 + c8 + 4]);
    float4 wb0 = *((const float4*)&W2[(size_t)(2 * i2 + 1) * 64 + c8]);
    float4 wb1 = *((const float4*)&W2[(size_t)(2 * i2 + 1) * 64 + c8 + 4]);
    a2[0] += h0 * wa0.x + h1v * wb0.x;
    a2[1] += h0 * wa0.y + h1v * wb0.y;
    a2[2] += h0 * wa0.z + h1v * wb0.z;
    a2[3] += h0 * wa0.w + h1v * wb0.w;
    a2[4] += h0 * wa1.x + h1v * wb1.x;
    a2[5] += h0 * wa1.y + h1v * wb1.y;
    a2[6] += h0 * wa1.z + h1v * wb1.z;
    a2[7] += h0 * wa1.w + h1v * wb1.w;
  }
  const int spair = s2 >> 1;
  const int shalf = s2 & 1;
  for (int i = 0; i < 420; ++i) {
    u32 fp2 = fT32[i * 18 + spair];
    float fv = shalf ? bfhi(fp2) : bflo(fp2);
    float4 wr0 = *((const float4*)&Wres[(size_t)i * 64 + c8]);
    float4 wr1 = *((const float4*)&Wres[(size_t)i * 64 + c8 + 4]);
    a2[0] += fv * wr0.x; a2[1] += fv * wr0.y;
    a2[2] += fv * wr0.z; a2[3] += fv * wr0.w;
    a2[4] += fv * wr1.x; a2[5] += fv * wr1.y;
    a2[6] += fv * wr1.z; a2[7] += fv * wr1.w;
  }

  float s1 = 0.f, sq = 0.f;
  #pragma unroll
  for (int e = 0; e < 8; ++e) { s1 += a2[e]; sq += a2[e] * a2[e]; }
  s1 += __shfl_xor(s1, 1); s1 += __shfl_xor(s1, 2); s1 += __shfl_xor(s1, 4);
  sq += __shfl_xor(sq, 1); sq += __shfl_xor(sq, 2); sq += __shfl_xor(sq, 4);
  float mean = s1 * (1.f / 64.f);
  float var = sq * (1.f / 64.f) - mean * mean;
  float inv = rsqrtf(var + LN_EPS);
  float pr = 0.f;
  #pragma unroll
  for (int e = 0; e < 8; ++e) {
    float n = (a2[e] - mean) * inv * g_ln[c8 + e] + b_ln[c8 + e];
    pr += n * W3[c8 + e];
  }
  pr += __shfl_xor(pr, 1); pr += __shfl_xor(pr, 2); pr += __shfl_xor(pr, 4);
  if ((t & 7) == 0 && (b0 + s2) < Btot) out[b0 + s2] = pr + b3[0];
}

extern "C" void kernel_launch(void* const* d_in, const int* in_sizes, int n_in,
                              void* d_out, int out_size, void* d_ws, size_t ws_size,
                              hipStream_t stream) {
  const float* x        = (const float*)d_in[0];
  const float* W_emb    = (const float*)d_in[1];
  const float* b_emb    = (const float*)d_in[2];
  const float* Wq       = (const float*)d_in[3];
  const float* bq       = (const float*)d_in[4];
  const float* Wk       = (const float*)d_in[5];
  const float* bk       = (const float*)d_in[6];
  const float* Wv       = (const float*)d_in[7];
  const float* bv       = (const float*)d_in[8];
  const float* Wo       = (const float*)d_in[9];
  const float* bo       = (const float*)d_in[10];
  const float* W_ff1    = (const float*)d_in[11];
  const float* W_ff2    = (const float*)d_in[12];
  const float* g_norm   = (const float*)d_in[13];
  const float* b_norm   = (const float*)d_in[14];
  const float* W_dy     = (const float*)d_in[15];
  const float* b_dy     = (const float*)d_in[16];
  const float* channels = (const float*)d_in[17];
  const float* W1       = (const float*)d_in[18];
  const float* b1       = (const float*)d_in[19];
  const float* W2       = (const float*)d_in[20];
  const float* b2       = (const float*)d_in[21];
  const float* Wres     = (const float*)d_in[22];
  const float* bres     = (const float*)d_in[23];
  const float* g_ln     = (const float*)d_in[24];
  const float* b_ln     = (const float*)d_in[25];
  const float* W3       = (const float*)d_in[26];
  const float* b3       = (const float*)d_in[27];

  const int B = in_sizes[0] / (LLEN * DMOD);
  u16* fbuf = (u16*)d_ws;   // B*420 bf16 ≈ 55 MB scratch

  fe_kernel<<<B, 64, 0, stream>>>(x, W_emb, b_emb, Wq, bq, Wk, bk, Wv, bv, Wo, bo,
                                  W_ff1, W_ff2, g_norm, b_norm, W_dy, b_dy, channels,
                                  fbuf);

  const int nb = (B + SB - 1) / SB;
  head_kernel<<<nb, 256, 0, stream>>>(fbuf, W1, b1, W2, b2, Wres, bres,
                                      g_ln, b_ln, W3, b3, (float*)d_out, B);
}